// Round 1
// baseline (5209.508 us; speedup 1.0000x reference)
//
#include <hip/hip_runtime.h>

// Problem constants
#define NAG   64          // agents per swarm (n)
#define RDIM  128         // attention hidden dim r
#define STR   68          // row stride (floats) for 128x64 LDS buffers (16B-align + conflict-free)
#define ASTR  65          // row stride for 64x64 A buffer

__device__ __forceinline__ float sigmoidf_(float v) {
    return 1.0f / (1.0f + __expf(-v));
}
__device__ __forceinline__ float siluf_(float v) {
    return v / (1.0f + __expf(-v));
}

// G[r][n] = act( sum_f W[r*F+f] * Xs[f*STR+n] ), for r in [0,128)
// 8 waves; wave w handles rows [16w,16w+16) in 2 groups of 8. lane = n.
// ACT: 0 = sigmoid, 1 = silu
template<int F, int ACT>
__device__ __forceinline__ void mm128_act(const float* __restrict__ W,
                                          const float* __restrict__ Xs,
                                          float* __restrict__ Gd,
                                          int w, int lane)
{
    #pragma unroll
    for (int g = 0; g < 2; ++g) {
        const int r0 = __builtin_amdgcn_readfirstlane(w * 16 + g * 8);
        float acc[8];
        #pragma unroll
        for (int j = 0; j < 8; ++j) acc[j] = 0.0f;
        #pragma unroll 2
        for (int f4 = 0; f4 < F / 4; ++f4) {
            const float xv0 = Xs[(4 * f4 + 0) * STR + lane];
            const float xv1 = Xs[(4 * f4 + 1) * STR + lane];
            const float xv2 = Xs[(4 * f4 + 2) * STR + lane];
            const float xv3 = Xs[(4 * f4 + 3) * STR + lane];
            #pragma unroll
            for (int j = 0; j < 8; ++j) {
                const float4 wv = *(const float4*)(W + (r0 + j) * F + 4 * f4);
                acc[j] = fmaf(wv.x, xv0, acc[j]);
                acc[j] = fmaf(wv.y, xv1, acc[j]);
                acc[j] = fmaf(wv.z, xv2, acc[j]);
                acc[j] = fmaf(wv.w, xv3, acc[j]);
            }
        }
        #pragma unroll
        for (int j = 0; j < 8; ++j) {
            const float v = acc[j];
            Gd[(r0 + j) * STR + lane] = (ACT == 0) ? sigmoidf_(v) : siluf_(v);
        }
    }
}

// S[n][m] = is * sum_r Qs[r][n]*Ks[r][m]; then row-softmax over m; result -> Ab[n][m]
// wave w handles rows n in [8w, 8w+8); lane = m. Softmax rows are wave-local (no barrier).
__device__ __forceinline__ void s_softmax_phase(const float* __restrict__ Qs_,
                                                const float* __restrict__ Ks_,
                                                float* __restrict__ Ab_,
                                                float is, int w, int lane)
{
    const int n0 = __builtin_amdgcn_readfirstlane(8 * w);
    float acc[8];
    #pragma unroll
    for (int j = 0; j < 8; ++j) acc[j] = 0.0f;
    for (int r = 0; r < RDIM; ++r) {
        const float kv = Ks_[r * STR + lane];
        const float4 q0 = *(const float4*)(Qs_ + r * STR + n0);       // broadcast b128
        const float4 q1 = *(const float4*)(Qs_ + r * STR + n0 + 4);
        acc[0] = fmaf(q0.x, kv, acc[0]);
        acc[1] = fmaf(q0.y, kv, acc[1]);
        acc[2] = fmaf(q0.z, kv, acc[2]);
        acc[3] = fmaf(q0.w, kv, acc[3]);
        acc[4] = fmaf(q1.x, kv, acc[4]);
        acc[5] = fmaf(q1.y, kv, acc[5]);
        acc[6] = fmaf(q1.z, kv, acc[6]);
        acc[7] = fmaf(q1.w, kv, acc[7]);
    }
    #pragma unroll
    for (int j = 0; j < 8; ++j) {
        const float v = acc[j] * is;
        float mx = v;
        #pragma unroll
        for (int o = 32; o >= 1; o >>= 1) mx = fmaxf(mx, __shfl_xor(mx, o));
        const float e = __expf(v - mx);
        float sm = e;
        #pragma unroll
        for (int o = 32; o >= 1; o >>= 1) sm += __shfl_xor(sm, o);
        Ab_[(n0 + j) * ASTR + lane] = e / sm;
    }
}

// O[r][n] = sum_m Vs[r][m] * Ab[n][m]; wave w handles rows r in [16w,16w+16); lane = n.
__device__ __forceinline__ void pv_phase(const float* __restrict__ Vs_,
                                         const float* __restrict__ Ab_,
                                         float* __restrict__ Os_,
                                         int w, int lane)
{
    const int r0 = __builtin_amdgcn_readfirstlane(16 * w);
    const int n = lane;
    float acc[16];
    #pragma unroll
    for (int j = 0; j < 16; ++j) acc[j] = 0.0f;
    #pragma unroll
    for (int mt = 0; mt < 4; ++mt) {
        float a[16];
        #pragma unroll
        for (int k = 0; k < 16; ++k) a[k] = Ab_[n * ASTR + mt * 16 + k];
        #pragma unroll
        for (int j = 0; j < 16; ++j) {
            const float* vr = Vs_ + (r0 + j) * STR + mt * 16;
            #pragma unroll
            for (int q4 = 0; q4 < 4; ++q4) {
                const float4 vv = *(const float4*)(vr + 4 * q4);      // broadcast b128
                acc[j] = fmaf(vv.x, a[4 * q4 + 0], acc[j]);
                acc[j] = fmaf(vv.y, a[4 * q4 + 1], acc[j]);
                acc[j] = fmaf(vv.z, a[4 * q4 + 2], acc[j]);
                acc[j] = fmaf(vv.w, a[4 * q4 + 3], acc[j]);
            }
        }
    }
    #pragma unroll
    for (int j = 0; j < 16; ++j) Os_[(r0 + j) * STR + n] = acc[j];
}

// Final projection: Ao5 (16 x 128) @ O (128 x 64) -> silu -> rch_b (16 x 64, global)
__device__ __forceinline__ void proj_final(const float* __restrict__ Ao5,
                                           const float* __restrict__ Os_,
                                           float* __restrict__ rch_b,
                                           int w, int lane)
{
    const int r0 = __builtin_amdgcn_readfirstlane(w * 2);
    float acc[2] = {0.0f, 0.0f};
    for (int f4 = 0; f4 < 32; ++f4) {
        const float xv0 = Os_[(4 * f4 + 0) * STR + lane];
        const float xv1 = Os_[(4 * f4 + 1) * STR + lane];
        const float xv2 = Os_[(4 * f4 + 2) * STR + lane];
        const float xv3 = Os_[(4 * f4 + 3) * STR + lane];
        #pragma unroll
        for (int j = 0; j < 2; ++j) {
            const float4 wv = *(const float4*)(Ao5 + (r0 + j) * 128 + 4 * f4);
            acc[j] = fmaf(wv.x, xv0, acc[j]);
            acc[j] = fmaf(wv.y, xv1, acc[j]);
            acc[j] = fmaf(wv.z, xv2, acc[j]);
            acc[j] = fmaf(wv.w, xv3, acc[j]);
        }
    }
    rch_b[(r0 + 0) * 64 + lane] = siluf_(acc[0]);
    rch_b[(r0 + 1) * 64 + lane] = siluf_(acc[1]);
}

__global__ __launch_bounds__(512, 1)
void swarm_attn_kernel(const float* __restrict__ x,  const float* __restrict__ L,
                       const float* __restrict__ Aq, const float* __restrict__ Ak,
                       const float* __restrict__ Av, const float* __restrict__ Aq1,
                       const float* __restrict__ Ak1,const float* __restrict__ Av1,
                       const float* __restrict__ Aq5,const float* __restrict__ Ak5,
                       const float* __restrict__ Av5,const float* __restrict__ Ao,
                       const float* __restrict__ Ao1,const float* __restrict__ Ao5,
                       float* __restrict__ rch)
{
    __shared__ float Xb[128 * STR];
    __shared__ float Qs[128 * STR];   // also reused as O
    __shared__ float Ks[128 * STR];
    __shared__ float Vs[128 * STR];
    __shared__ float Ab[64 * ASTR];
    __shared__ float s_inv;

    const int b    = blockIdx.x;
    const int tid  = threadIdx.x;
    const int w    = tid >> 6;
    const int lane = tid & 63;

    // Layer-1 input: x[b] is (8, 64); wave w = feature row f
    Xb[w * STR + lane] = x[(size_t)b * 512 + w * 64 + lane];

    // num_nb = popcount(L[b,0,:] >= 1) + 1 ; is = 1/sqrt(num_nb)
    if (w == 0) {
        const float lv = L[(size_t)b * 512 + lane];
        const unsigned long long msk = __ballot(lv >= 1.0f);
        if (lane == 0) s_inv = __frsqrt_rn((float)(__popcll(msk) + 1));
    }
    __syncthreads();
    const float is = s_inv;

    // ---------------- Layer 1 (F = 8) ----------------
    mm128_act<8, 0>(Aq, Xb, Qs, w, lane);
    mm128_act<8, 0>(Ak, Xb, Ks, w, lane);
    mm128_act<8, 0>(Av, Xb, Vs, w, lane);
    __syncthreads();
    s_softmax_phase(Qs, Ks, Ab, is, w, lane);
    __syncthreads();
    pv_phase(Vs, Ab, Qs, w, lane);            // O -> Qs
    __syncthreads();
    mm128_act<128, 1>(Ao, Qs, Xb, w, lane);   // R -> Xb
    __syncthreads();

    // ---------------- Layer 2 (F = 128) ----------------
    mm128_act<128, 0>(Aq1, Xb, Qs, w, lane);
    mm128_act<128, 0>(Ak1, Xb, Ks, w, lane);
    mm128_act<128, 0>(Av1, Xb, Vs, w, lane);
    __syncthreads();
    s_softmax_phase(Qs, Ks, Ab, is, w, lane);
    __syncthreads();
    pv_phase(Vs, Ab, Qs, w, lane);
    __syncthreads();
    mm128_act<128, 1>(Ao1, Qs, Xb, w, lane);
    __syncthreads();

    // ---------------- Layer 3 (F = 128) ----------------
    mm128_act<128, 0>(Aq5, Xb, Qs, w, lane);
    mm128_act<128, 0>(Ak5, Xb, Ks, w, lane);
    mm128_act<128, 0>(Av5, Xb, Vs, w, lane);
    __syncthreads();
    s_softmax_phase(Qs, Ks, Ab, is, w, lane);
    __syncthreads();
    pv_phase(Vs, Ab, Qs, w, lane);
    __syncthreads();
    proj_final(Ao5, Qs, rch + (size_t)b * 1024, w, lane);
}

// Output assembly: per swarm s, M_g[i][j] = sum_{c=0..3} rch[s*64+i][4g+c][j]
// out diag  = rs[2ub][i]+rs[2ub+1][i]+cs[ub][i]+cs[2+ub][i]
// out offdg = -(p==q) * (M_g[i][j]^2 + M_gT[j][i]^2), g=2ub+vb, gT=2vb+ub
__global__ __launch_bounds__(256, 1)
void assemble_kernel(const float* __restrict__ rch, float* __restrict__ out)
{
    __shared__ float Msh[4 * 64 * ASTR];
    __shared__ float rs[4][64];
    __shared__ float cs[4][64];
    const int s = blockIdx.x;
    const int t = threadIdx.x;

    // Load + channel-sum (reads possibly aliased region; all reads precede writes)
    for (int e = t; e < 4 * 64 * 64; e += 256) {
        const int j = e & 63, i = (e >> 6) & 63, g = e >> 12;
        const float* p = rch + ((size_t)s * 64 + i) * 1024 + (4 * g) * 64 + j;
        Msh[(g * 64 + i) * ASTR + j] = p[0] + p[64] + p[128] + p[192];
    }
    __syncthreads();
    {
        const int g = t >> 6, i = t & 63;
        float r2 = 0.0f, c2 = 0.0f;
        for (int j = 0; j < 64; ++j) {
            const float a  = Msh[(g * 64 + i) * ASTR + j];
            const float bb = Msh[(g * 64 + j) * ASTR + i];
            r2 = fmaf(a, a, r2);
            c2 = fmaf(bb, bb, c2);
        }
        rs[g][i] = r2;
        cs[g][i] = c2;
    }
    __syncthreads();

    const int v  = t;
    const int vb = v >> 7, jj = (v >> 1) & 63, q = v & 1;
    float* outs = out + (size_t)s * 65536;
    for (int u = 0; u < 256; ++u) {
        const int ub = u >> 7, ii = (u >> 1) & 63, p = u & 1;
        float val = 0.0f;
        if (u == v) {
            val = rs[2 * ub][ii] + rs[2 * ub + 1][ii] + cs[ub][ii] + cs[2 + ub][ii];
        } else if (p == q) {
            const int g = 2 * ub + vb, gT = 2 * vb + ub;
            const float a  = Msh[(g * 64 + ii) * ASTR + jj];
            const float bb = Msh[(gT * 64 + jj) * ASTR + ii];
            val = -(a * a + bb * bb);
        }
        outs[u * 256 + v] = val;
    }
}

extern "C" void kernel_launch(void* const* d_in, const int* in_sizes, int n_in,
                              void* d_out, int out_size, void* d_ws, size_t ws_size,
                              hipStream_t stream)
{
    const float* x   = (const float*)d_in[0];
    const float* L   = (const float*)d_in[1];
    const float* Aq  = (const float*)d_in[2];
    const float* Ak  = (const float*)d_in[3];
    const float* Av  = (const float*)d_in[4];
    const float* Aq1 = (const float*)d_in[5];
    const float* Ak1 = (const float*)d_in[6];
    const float* Av1 = (const float*)d_in[7];
    const float* Aq5 = (const float*)d_in[8];
    const float* Ak5 = (const float*)d_in[9];
    const float* Av5 = (const float*)d_in[10];
    const float* Ao  = (const float*)d_in[11];
    const float* Ao1 = (const float*)d_in[12];
    const float* Ao5 = (const float*)d_in[13];
    float* out = (float*)d_out;

    const size_t need = (size_t)8192 * 1024 * sizeof(float);   // 33.5 MB staging
    float* rch = (ws_size >= need) ? (float*)d_ws : out;       // fallback: stage in d_out

    swarm_attn_kernel<<<8192, 512, 0, stream>>>(x, L, Aq, Ak, Av, Aq1, Ak1, Av1,
                                                Aq5, Ak5, Av5, Ao, Ao1, Ao5, rch);
    assemble_kernel<<<128, 256, 0, stream>>>(rch, out);
}

// Round 3
// 554.099 us; speedup vs baseline: 9.4018x; 9.4018x over previous
//
#include <hip/hip_runtime.h>
#include <hip/hip_bf16.h>

typedef _Float16 f16;
typedef __attribute__((ext_vector_type(8))) _Float16 h8v;  // 8 fp16 = 4 VGPR
typedef __attribute__((ext_vector_type(4))) float f4v;     // 4 f32 acc

// fp16 weight workspace layout (elements)
#define OFF_WQ  0
#define OFF_WK  4096
#define OFF_WV  8192
#define OFF_AQ1 12288
#define OFF_AK1 28672
#define OFF_AV1 45056
#define OFF_AQ5 61440
#define OFF_AK5 77824
#define OFF_AV5 94208
#define OFF_AO  110592
#define OFF_AO1 126976
#define OFF_AO5 143360
#define WTS_TOTAL 145408

__device__ __forceinline__ f4v mfma_(h8v a, h8v b, f4v c) {
  return __builtin_amdgcn_mfma_f32_16x16x32_f16(a, b, c, 0, 0, 0);
}

// XOR-swizzled LDS addressing (T2): pitch 256B ([64][128] f16) and 128B ([*][64] f16)
__device__ __forceinline__ f16* swz256(f16* b, int n, int k) {
  int byte = (n << 8) + (k << 1); byte ^= (n & 7) << 4;
  return (f16*)((char*)b + byte);
}
__device__ __forceinline__ const f16* swz256c(const f16* b, int n, int k) {
  int byte = (n << 8) + (k << 1); byte ^= (n & 7) << 4;
  return (const f16*)((const char*)b + byte);
}
__device__ __forceinline__ f16* swz128(f16* b, int r, int m) {
  int byte = (r << 7) + (m << 1); byte ^= (r & 7) << 4;
  return (f16*)((char*)b + byte);
}
__device__ __forceinline__ const f16* swz128c(const f16* b, int r, int m) {
  int byte = (r << 7) + (m << 1); byte ^= (r & 7) << 4;
  return (const f16*)((const char*)b + byte);
}

// ACT: 0 sigmoid, 1 silu, 2 none — applied in f32, packed to 4 fp16 (b64)
template<int ACT>
__device__ __forceinline__ unsigned long long pack4act(f4v acc) {
  union { unsigned long long u64; f16 h[4]; } u;
  #pragma unroll
  for (int j = 0; j < 4; ++j) {
    float v = acc[j];
    if (ACT == 0)      v = 1.0f / (1.0f + __expf(-v));
    else if (ACT == 1) v = v / (1.0f + __expf(-v));
    u.h[j] = (f16)v;
  }
  return u.u64;
}

// G = act(W @ X): M=128 rows of W, N=64 agents, K=NK*32.
// W row-major fp16 global [128][NK*32]; Bsrc = X^T LDS [n][k] swz256.
// Output transposed: OutT[n][r] swz256. Wave w owns r-tile w.
template<int NK, int ACT>
__device__ __forceinline__ void mm_WX(const f16* __restrict__ Wg,
                                      const f16* __restrict__ Bsrc,
                                      f16* __restrict__ OutT,
                                      int w, int lane)
{
  const int lrow = lane & 15, lk = lane >> 4;
  const int r0 = 16 * w;
  h8v a[NK];
  #pragma unroll
  for (int kk = 0; kk < NK; ++kk)
    a[kk] = *(const h8v*)(Wg + (r0 + lrow) * (NK * 32) + kk * 32 + lk * 8);
  #pragma unroll
  for (int nt = 0; nt < 4; ++nt) {
    f4v acc = {0.f, 0.f, 0.f, 0.f};
    #pragma unroll
    for (int kk = 0; kk < NK; ++kk) {
      h8v bf = *(const h8v*)swz256c(Bsrc, nt * 16 + lrow, kk * 32 + lk * 8);
      acc = mfma_(a[kk], bf, acc);
    }
    // D: col = n = nt*16+lrow, rows r0+lk*4+j
    *(unsigned long long*)swz256(OutT, nt * 16 + lrow, r0 + lk * 4) = pack4act<ACT>(acc);
  }
}

// V^T form: Vt = act(X^T @ Av^T): M=64 (n), N=128 (r), K=NK*32.
// Output natural V[r][n] swz128 (what PV's A-operand wants). Wave w owns r-col-tile w.
template<int NK>
__device__ __forceinline__ void mm_VT(const f16* __restrict__ Wg,
                                      const f16* __restrict__ XtL,
                                      f16* __restrict__ VL,
                                      int w, int lane)
{
  const int lrow = lane & 15, lk = lane >> 4;
  const int c0 = 16 * w;   // r columns
  h8v bfr[NK];
  #pragma unroll
  for (int kk = 0; kk < NK; ++kk)
    bfr[kk] = *(const h8v*)(Wg + (c0 + lrow) * (NK * 32) + kk * 32 + lk * 8);
  #pragma unroll
  for (int nt = 0; nt < 4; ++nt) {
    f4v acc = {0.f, 0.f, 0.f, 0.f};
    #pragma unroll
    for (int kk = 0; kk < NK; ++kk) {
      h8v af = *(const h8v*)swz256c(XtL, nt * 16 + lrow, kk * 32 + lk * 8);
      acc = mfma_(af, bfr[kk], acc);
    }
    // D: col = r = c0+lrow, rows n = nt*16+lk*4+j -> V[r][n..n+3]
    *(unsigned long long*)swz128(VL, c0 + lrow, nt * 16 + lk * 4) = pack4act<0>(acc);
  }
}

// S^T[m][n] = sum_r K[r][m] Q[r][n], scale, softmax over m (wave-local), P -> Ps[n][m].
// Waves 0..3 only; wave w owns n-tile w (16 n-columns, all 64 m in-register).
__device__ __forceinline__ void s_softmax(const f16* __restrict__ QtL,
                                          const f16* __restrict__ KtL,
                                          f16* __restrict__ PsL,
                                          float is, int w, int lane)
{
  const int lrow = lane & 15, lk = lane >> 4;
  const int n = 16 * w + lrow;
  h8v bq[4];
  #pragma unroll
  for (int kk = 0; kk < 4; ++kk)
    bq[kk] = *(const h8v*)swz256c(QtL, n, kk * 32 + lk * 8);
  f4v acc[4];
  #pragma unroll
  for (int mt = 0; mt < 4; ++mt) {
    acc[mt] = (f4v){0.f, 0.f, 0.f, 0.f};
    #pragma unroll
    for (int kk = 0; kk < 4; ++kk) {
      h8v ak = *(const h8v*)swz256c(KtL, mt * 16 + lrow, kk * 32 + lk * 8);
      acc[mt] = mfma_(ak, bq[kk], acc[mt]);
    }
  }
  // lane holds S^T[m = mt*16+lk*4+j][n]; reduce 16 regs + lane-groups {n,n+16,n+32,n+48}
  float mx = -1e30f;
  #pragma unroll
  for (int mt = 0; mt < 4; ++mt)
    #pragma unroll
    for (int j = 0; j < 4; ++j) { acc[mt][j] *= is; mx = fmaxf(mx, acc[mt][j]); }
  mx = fmaxf(mx, __shfl_xor(mx, 16));
  mx = fmaxf(mx, __shfl_xor(mx, 32));
  float sm = 0.f;
  #pragma unroll
  for (int mt = 0; mt < 4; ++mt)
    #pragma unroll
    for (int j = 0; j < 4; ++j) { acc[mt][j] = __expf(acc[mt][j] - mx); sm += acc[mt][j]; }
  sm += __shfl_xor(sm, 16);
  sm += __shfl_xor(sm, 32);
  const float inv = 1.0f / sm;
  #pragma unroll
  for (int mt = 0; mt < 4; ++mt) {
    union { unsigned long long u64; f16 h[4]; } u;
    #pragma unroll
    for (int j = 0; j < 4; ++j) u.h[j] = (f16)(acc[mt][j] * inv);
    *(unsigned long long*)swz128(PsL, n, mt * 16 + lk * 4) = u.u64;
  }
}

// O = V @ P^T: M=128 (r), N=64 (n), K=64 (m). Output Ot[n][r] swz256 (no act).
__device__ __forceinline__ void mm_PV(const f16* __restrict__ VL,
                                      const f16* __restrict__ PsL,
                                      f16* __restrict__ OtL,
                                      int w, int lane)
{
  const int lrow = lane & 15, lk = lane >> 4;
  const int r0 = 16 * w;
  h8v av[2];
  #pragma unroll
  for (int kk = 0; kk < 2; ++kk)
    av[kk] = *(const h8v*)swz128c(VL, r0 + lrow, kk * 32 + lk * 8);
  #pragma unroll
  for (int nt = 0; nt < 4; ++nt) {
    f4v acc = {0.f, 0.f, 0.f, 0.f};
    #pragma unroll
    for (int kk = 0; kk < 2; ++kk) {
      h8v bp = *(const h8v*)swz128c(PsL, nt * 16 + lrow, kk * 32 + lk * 8);
      acc = mfma_(av[kk], bp, acc);
    }
    *(unsigned long long*)swz256(OtL, nt * 16 + lrow, r0 + lk * 4) = pack4act<2>(acc);
  }
}

// Final: rch[b][s][n] = silu(Ao5(16x128) @ O(128x64)), fp32 out. Waves 0..3, n-tile w.
__device__ __forceinline__ void mm_final(const f16* __restrict__ Ao5g,
                                         const f16* __restrict__ OtL,
                                         float* __restrict__ rch_b, int w, int lane)
{
  const int lrow = lane & 15, lk = lane >> 4;
  h8v a[4];
  #pragma unroll
  for (int kk = 0; kk < 4; ++kk)
    a[kk] = *(const h8v*)(Ao5g + lrow * 128 + kk * 32 + lk * 8);
  const int n = 16 * w + lrow;
  f4v acc = {0.f, 0.f, 0.f, 0.f};
  #pragma unroll
  for (int kk = 0; kk < 4; ++kk) {
    h8v b = *(const h8v*)swz256c(OtL, n, kk * 32 + lk * 8);
    acc = mfma_(a[kk], b, acc);
  }
  #pragma unroll
  for (int j = 0; j < 4; ++j) {
    float v = acc[j];
    v = v / (1.0f + __expf(-v));
    rch_b[(lk * 4 + j) * 64 + n] = v;   // s = lk*4+j in [0,16)
  }
}

__global__ __launch_bounds__(512, 4)
void swarm_attn_mfma(const float* __restrict__ x, const float* __restrict__ L,
                     const f16* __restrict__ wts, float* __restrict__ rch)
{
  __shared__ f16 Xt[64 * 128];  // X^T / R^T [n][k] swz256
  __shared__ f16 Qt[64 * 128];  // Q^T [n][r]; reused as O^T after S
  __shared__ f16 Kt[64 * 128];  // K^T [m][r]
  __shared__ f16 Vb[128 * 64];  // V [r][m] swz128
  __shared__ f16 Ps[64 * 64];   // P [n][m] swz128
  __shared__ float s_inv;

  const int b = blockIdx.x;
  const int tid = threadIdx.x;
  const int w = tid >> 6, lane = tid & 63;

  // stage layer-1 X^T [n][f], zero-padded to K=32
  for (int e = tid; e < 64 * 32; e += 512) {
    const int n = e >> 5, f = e & 31;
    const float v = (f < 8) ? x[(size_t)b * 512 + f * 64 + n] : 0.f;
    *swz256(Xt, n, f) = (f16)v;
  }
  if (w == 0) {
    const float lv = L[(size_t)b * 512 + lane];
    const unsigned long long msk = __ballot(lv >= 1.0f);
    if (lane == 0) s_inv = __frsqrt_rn((float)(__popcll(msk) + 1));
  }
  __syncthreads();
  const float is = s_inv;

  // -------- Layer 1 (K = 32 padded) --------
  mm_WX<1, 0>(wts + OFF_WQ, Xt, Qt, w, lane);
  mm_WX<1, 0>(wts + OFF_WK, Xt, Kt, w, lane);
  mm_VT<1>  (wts + OFF_WV, Xt, Vb, w, lane);
  __syncthreads();
  if (w < 4) s_softmax(Qt, Kt, Ps, is, w, lane);
  __syncthreads();
  mm_PV(Vb, Ps, Qt, w, lane);                 // O^T -> Qt
  __syncthreads();
  mm_WX<4, 1>(wts + OFF_AO, Qt, Xt, w, lane); // R^T -> Xt
  __syncthreads();

  // -------- Layer 2 --------
  mm_WX<4, 0>(wts + OFF_AQ1, Xt, Qt, w, lane);
  mm_WX<4, 0>(wts + OFF_AK1, Xt, Kt, w, lane);
  mm_VT<4>  (wts + OFF_AV1, Xt, Vb, w, lane);
  __syncthreads();
  if (w < 4) s_softmax(Qt, Kt, Ps, is, w, lane);
  __syncthreads();
  mm_PV(Vb, Ps, Qt, w, lane);
  __syncthreads();
  mm_WX<4, 1>(wts + OFF_AO1, Qt, Xt, w, lane);
  __syncthreads();

  // -------- Layer 3 --------
  mm_WX<4, 0>(wts + OFF_AQ5, Xt, Qt, w, lane);
  mm_WX<4, 0>(wts + OFF_AK5, Xt, Kt, w, lane);
  mm_VT<4>  (wts + OFF_AV5, Xt, Vb, w, lane);
  __syncthreads();
  if (w < 4) s_softmax(Qt, Kt, Ps, is, w, lane);
  __syncthreads();
  mm_PV(Vb, Ps, Qt, w, lane);
  __syncthreads();
  if (w < 4) mm_final(wts + OFF_AO5, Qt, rch + (size_t)b * 1024, w, lane);
}

// Convert all weights to fp16 (layer-1 zero-padded 8->32)
__global__ void conv_wts(const float* Aq, const float* Ak, const float* Av,
                         const float* Aq1, const float* Ak1, const float* Av1,
                         const float* Aq5, const float* Ak5, const float* Av5,
                         const float* Ao, const float* Ao1, const float* Ao5,
                         f16* wts)
{
  const int t = blockIdx.x * 256 + threadIdx.x;
  if (t >= WTS_TOTAL) return;
  float v;
  if (t < 12288) {
    const int m = t >> 12, idx = t & 4095, r = idx >> 5, f = idx & 31;
    const float* W = (m == 0) ? Aq : (m == 1) ? Ak : Av;
    v = (f < 8) ? W[r * 8 + f] : 0.f;
  } else if (t < 143360) {
    const int idx = t - 12288, m = idx >> 14, e = idx & 16383;
    const float* W = (m == 0) ? Aq1 : (m == 1) ? Ak1 : (m == 2) ? Av1 :
                     (m == 3) ? Aq5 : (m == 4) ? Ak5 : (m == 5) ? Av5 :
                     (m == 6) ? Ao : Ao1;
    v = W[e];
  } else {
    v = Ao5[t - 143360];
  }
  wts[t] = (f16)v;
}

// Stage A: per swarm, channel-sum M_g (4x64x64) + row/col sums of squares
#define ASTR 65
__global__ __launch_bounds__(256, 1)
void reduce_kernel(const float* __restrict__ rch, float* __restrict__ Mw,
                   float* __restrict__ rsw, float* __restrict__ csw)
{
  __shared__ float Msh[4 * 64 * ASTR];
  const int s = blockIdx.x, t = threadIdx.x;
  for (int e = t; e < 16384; e += 256) {
    const int j = e & 63, i = (e >> 6) & 63, g = e >> 12;
    const float* p = rch + ((size_t)s * 64 + i) * 1024 + (4 * g) * 64 + j;
    const float v = p[0] + p[64] + p[128] + p[192];
    Msh[(g * 64 + i) * ASTR + j] = v;
    Mw[(size_t)s * 16384 + e] = v;        // [s][g][i][j]
  }
  __syncthreads();
  const int g = t >> 6, i = t & 63;
  float r2 = 0.f, c2 = 0.f;
  for (int j = 0; j < 64; ++j) {
    const float a = Msh[(g * 64 + i) * ASTR + j];
    const float bb = Msh[(g * 64 + j) * ASTR + i];
    r2 = fmaf(a, a, r2);
    c2 = fmaf(bb, bb, c2);
  }
  rsw[s * 256 + g * 64 + i] = r2;
  csw[s * 256 + g * 64 + i] = c2;
}

// Stage B: fully-parallel expansion to the 256x256 output per swarm (no rch reads)
__global__ __launch_bounds__(256, 1)
void expand_kernel(const float* __restrict__ Mw, const float* __restrict__ rsw,
                   const float* __restrict__ csw, float* __restrict__ out)
{
  const size_t e = ((size_t)blockIdx.x * 256 + threadIdx.x) * 4;
  const int s = (int)(e >> 16);
  const int rem = (int)(e & 65535);
  const int u = rem >> 8, v0 = rem & 255;
  const int ub = u >> 7, ii = (u & 127) >> 1, p = u & 1;
  const float* Ms = Mw + (size_t)s * 16384;
  float4 o;
  float* po = &o.x;
  #pragma unroll
  for (int c = 0; c < 4; ++c) {
    const int v = v0 + c;
    const int vb = v >> 7, jj = (v & 127) >> 1, q = v & 1;
    float val = 0.f;
    if (u == v) {
      val = rsw[s * 256 + (2 * ub) * 64 + ii] + rsw[s * 256 + (2 * ub + 1) * 64 + ii]
          + csw[s * 256 + ub * 64 + ii] + csw[s * 256 + (2 + ub) * 64 + ii];
    } else if (p == q) {
      const int g = 2 * ub + vb, gp = 2 * vb + ub;
      const float a = Ms[g * 4096 + ii * 64 + jj];
      const float bb = Ms[gp * 4096 + jj * 64 + ii];
      val = -(a * a + bb * bb);
    }
    po[c] = val;
  }
  *(float4*)(out + e) = o;
}

extern "C" void kernel_launch(void* const* d_in, const int* in_sizes, int n_in,
                              void* d_out, int out_size, void* d_ws, size_t ws_size,
                              hipStream_t stream)
{
  const float* x   = (const float*)d_in[0];
  const float* L   = (const float*)d_in[1];
  const float* Aq  = (const float*)d_in[2];
  const float* Ak  = (const float*)d_in[3];
  const float* Av  = (const float*)d_in[4];
  const float* Aq1 = (const float*)d_in[5];
  const float* Ak1 = (const float*)d_in[6];
  const float* Av1 = (const float*)d_in[7];
  const float* Aq5 = (const float*)d_in[8];
  const float* Ak5 = (const float*)d_in[9];
  const float* Av5 = (const float*)d_in[10];
  const float* Ao  = (const float*)d_in[11];
  const float* Ao1 = (const float*)d_in[12];
  const float* Ao5 = (const float*)d_in[13];

  // ws: fp16 weights (290816 B) | Mw 128*16384 f32 (8.39 MB) | rsw | csw
  f16* wts = (f16*)d_ws;
  float* Mw  = (float*)((char*)d_ws + (size_t)WTS_TOTAL * 2);
  float* rsw = Mw + (size_t)128 * 16384;
  float* csw = rsw + 128 * 256;
  // rch (8192x16x64 f32 = 33.55 MB) staged in d_out — exactly out_size; expand_kernel
  // reads only Mw/rsw/csw, so overwriting d_out afterwards is race-free.
  float* rch = (float*)d_out;

  conv_wts<<<(WTS_TOTAL + 255) / 256, 256, 0, stream>>>(Aq, Ak, Av, Aq1, Ak1, Av1,
                                                        Aq5, Ak5, Av5, Ao, Ao1, Ao5, wts);
  swarm_attn_mfma<<<8192, 512, 0, stream>>>(x, L, wts, rch);
  reduce_kernel<<<128, 256, 0, stream>>>(rch, Mw, rsw, csw);
  expand_kernel<<<8192, 256, 0, stream>>>(Mw, rsw, csw, (float*)d_out);
}

// Round 5
// 408.671 us; speedup vs baseline: 12.7474x; 1.3559x over previous
//
#include <hip/hip_runtime.h>
#include <hip/hip_bf16.h>

typedef _Float16 f16;
typedef __attribute__((ext_vector_type(8))) _Float16 h8v;  // 8 fp16 = 4 VGPR
typedef __attribute__((ext_vector_type(4))) float f4v;     // 4 f32 acc

// fp16 weight workspace layout (elements)
#define OFF_WQ  0
#define OFF_WK  4096
#define OFF_WV  8192
#define OFF_AQ1 12288
#define OFF_AK1 28672
#define OFF_AV1 45056
#define OFF_AQ5 61440
#define OFF_AK5 77824
#define OFF_AV5 94208
#define OFF_AO  110592
#define OFF_AO1 126976
#define OFF_AO5 143360
#define WTS_TOTAL 145408

__device__ __forceinline__ f4v mfma_(h8v a, h8v b, f4v c) {
  return __builtin_amdgcn_mfma_f32_16x16x32_f16(a, b, c, 0, 0, 0);
}
__device__ __forceinline__ float rcp_(float x) { return __builtin_amdgcn_rcpf(x); }

// pack 2 f32 -> 2 f16 (v_cvt_pkrtz_f16_f32, single instruction)
__device__ __forceinline__ unsigned int pk2(float a, float b) {
  __fp16 __attribute__((ext_vector_type(2))) h2 = __builtin_amdgcn_cvt_pkrtz(a, b);
  return *reinterpret_cast<unsigned int*>(&h2);
}

// XOR-swizzled LDS addressing (T2): pitch 256B ([64][128] f16) and 128B ([*][64] f16)
__device__ __forceinline__ f16* swz256(f16* b, int n, int k) {
  int byte = (n << 8) + (k << 1); byte ^= (n & 7) << 4;
  return (f16*)((char*)b + byte);
}
__device__ __forceinline__ const f16* swz256c(const f16* b, int n, int k) {
  int byte = (n << 8) + (k << 1); byte ^= (n & 7) << 4;
  return (const f16*)((const char*)b + byte);
}
__device__ __forceinline__ f16* swz128(f16* b, int r, int m) {
  int byte = (r << 7) + (m << 1); byte ^= (r & 7) << 4;
  return (f16*)((char*)b + byte);
}
__device__ __forceinline__ const f16* swz128c(const f16* b, int r, int m) {
  int byte = (r << 7) + (m << 1); byte ^= (r & 7) << 4;
  return (const f16*)((const char*)b + byte);
}

// ACT: 0 sigmoid, 1 silu, 2 none — applied in f32 (v_rcp, no slow div), packed to 4 f16
template<int ACT>
__device__ __forceinline__ unsigned long long pack4act(f4v acc) {
  float v[4];
  #pragma unroll
  for (int j = 0; j < 4; ++j) {
    float t = acc[j];
    if (ACT == 0)      t = rcp_(1.0f + __expf(-t));
    else if (ACT == 1) t = t * rcp_(1.0f + __expf(-t));
    v[j] = t;
  }
  union { unsigned long long u64; unsigned int u32[2]; } u;
  u.u32[0] = pk2(v[0], v[1]);
  u.u32[1] = pk2(v[2], v[3]);
  return u.u64;
}

// G = act(W @ X): M=128 rows of W, N=64 agents, K=NK*32.
// W row-major fp16 global [128][NK*32]; Bsrc = X^T LDS [n][k] swz256.
// Output transposed: OutT[n][r] swz256. Wave w owns r-tile w.
template<int NK, int ACT>
__device__ __forceinline__ void mm_WX(const f16* __restrict__ Wg,
                                      const f16* __restrict__ Bsrc,
                                      f16* __restrict__ OutT,
                                      int w, int lane)
{
  const int lrow = lane & 15, lk = lane >> 4;
  const int r0 = 16 * w;
  h8v a[NK];
  #pragma unroll
  for (int kk = 0; kk < NK; ++kk)
    a[kk] = *(const h8v*)(Wg + (r0 + lrow) * (NK * 32) + kk * 32 + lk * 8);
  #pragma unroll
  for (int nt = 0; nt < 4; ++nt) {
    f4v acc = {0.f, 0.f, 0.f, 0.f};
    #pragma unroll
    for (int kk = 0; kk < NK; ++kk) {
      h8v bf = *(const h8v*)swz256c(Bsrc, nt * 16 + lrow, kk * 32 + lk * 8);
      acc = mfma_(a[kk], bf, acc);
    }
    // D: col = n = nt*16+lrow, rows r0+lk*4+j
    *(unsigned long long*)swz256(OutT, nt * 16 + lrow, r0 + lk * 4) = pack4act<ACT>(acc);
  }
}

// V^T form: Vt = act(X^T @ Av^T): M=64 (n), N=128 (r), K=NK*32.
// Output natural V[r][n] swz128 (what PV's A-operand wants). Wave w owns r-col-tile w.
template<int NK>
__device__ __forceinline__ void mm_VT(const f16* __restrict__ Wg,
                                      const f16* __restrict__ XtL,
                                      f16* __restrict__ VL,
                                      int w, int lane)
{
  const int lrow = lane & 15, lk = lane >> 4;
  const int c0 = 16 * w;   // r columns
  h8v bfr[NK];
  #pragma unroll
  for (int kk = 0; kk < NK; ++kk)
    bfr[kk] = *(const h8v*)(Wg + (c0 + lrow) * (NK * 32) + kk * 32 + lk * 8);
  #pragma unroll
  for (int nt = 0; nt < 4; ++nt) {
    f4v acc = {0.f, 0.f, 0.f, 0.f};
    #pragma unroll
    for (int kk = 0; kk < NK; ++kk) {
      h8v af = *(const h8v*)swz256c(XtL, nt * 16 + lrow, kk * 32 + lk * 8);
      acc = mfma_(af, bfr[kk], acc);
    }
    // D: col = r = c0+lrow, rows n = nt*16+lk*4+j -> V[r][n..n+3]
    *(unsigned long long*)swz128(VL, c0 + lrow, nt * 16 + lk * 4) = pack4act<0>(acc);
  }
}

// S^T[m][n] = sum_r K[r][m] Q[r][n], scale, softmax over m (wave-local), P -> Ps[n][m].
// Waves 0..3 only; wave w owns n-tile w (16 n-columns, all 64 m in-register).
__device__ __forceinline__ void s_softmax(const f16* __restrict__ QtL,
                                          const f16* __restrict__ KtL,
                                          f16* __restrict__ PsL,
                                          float is, int w, int lane)
{
  const int lrow = lane & 15, lk = lane >> 4;
  const int n = 16 * w + lrow;
  h8v bq[4];
  #pragma unroll
  for (int kk = 0; kk < 4; ++kk)
    bq[kk] = *(const h8v*)swz256c(QtL, n, kk * 32 + lk * 8);
  f4v acc[4];
  #pragma unroll
  for (int mt = 0; mt < 4; ++mt) {
    acc[mt] = (f4v){0.f, 0.f, 0.f, 0.f};
    #pragma unroll
    for (int kk = 0; kk < 4; ++kk) {
      h8v ak = *(const h8v*)swz256c(KtL, mt * 16 + lrow, kk * 32 + lk * 8);
      acc[mt] = mfma_(ak, bq[kk], acc[mt]);
    }
  }
  // lane holds S^T[m = mt*16+lk*4+j][n]; reduce 16 regs + lane-groups {n,n+16,n+32,n+48}
  float mx = -1e30f;
  #pragma unroll
  for (int mt = 0; mt < 4; ++mt)
    #pragma unroll
    for (int j = 0; j < 4; ++j) { acc[mt][j] *= is; mx = fmaxf(mx, acc[mt][j]); }
  mx = fmaxf(mx, __shfl_xor(mx, 16));
  mx = fmaxf(mx, __shfl_xor(mx, 32));
  float sm = 0.f;
  #pragma unroll
  for (int mt = 0; mt < 4; ++mt)
    #pragma unroll
    for (int j = 0; j < 4; ++j) { acc[mt][j] = __expf(acc[mt][j] - mx); sm += acc[mt][j]; }
  sm += __shfl_xor(sm, 16);
  sm += __shfl_xor(sm, 32);
  const float inv = rcp_(sm);
  #pragma unroll
  for (int mt = 0; mt < 4; ++mt) {
    union { unsigned long long u64; unsigned int u32[2]; } u;
    u.u32[0] = pk2(acc[mt][0] * inv, acc[mt][1] * inv);
    u.u32[1] = pk2(acc[mt][2] * inv, acc[mt][3] * inv);
    *(unsigned long long*)swz128(PsL, n, mt * 16 + lk * 4) = u.u64;
  }
}

// O = V @ P^T: M=128 (r), N=64 (n), K=64 (m). Output Ot[n][r] swz256 (no act).
__device__ __forceinline__ void mm_PV(const f16* __restrict__ VL,
                                      const f16* __restrict__ PsL,
                                      f16* __restrict__ OtL,
                                      int w, int lane)
{
  const int lrow = lane & 15, lk = lane >> 4;
  const int r0 = 16 * w;
  h8v av[2];
  #pragma unroll
  for (int kk = 0; kk < 2; ++kk)
    av[kk] = *(const h8v*)swz128c(VL, r0 + lrow, kk * 32 + lk * 8);
  #pragma unroll
  for (int nt = 0; nt < 4; ++nt) {
    f4v acc = {0.f, 0.f, 0.f, 0.f};
    #pragma unroll
    for (int kk = 0; kk < 2; ++kk) {
      h8v bp = *(const h8v*)swz128c(PsL, nt * 16 + lrow, kk * 32 + lk * 8);
      acc = mfma_(av[kk], bp, acc);
    }
    *(unsigned long long*)swz256(OtL, nt * 16 + lrow, r0 + lk * 4) = pack4act<2>(acc);
  }
}

// Final: rch[b][s][n] = silu(Ao5(16x128) @ O(128x64)), fp32 out. Waves 0..3, n-tile w.
__device__ __forceinline__ void mm_final(const f16* __restrict__ Ao5g,
                                         const f16* __restrict__ OtL,
                                         float* __restrict__ rch_b, int w, int lane)
{
  const int lrow = lane & 15, lk = lane >> 4;
  h8v a[4];
  #pragma unroll
  for (int kk = 0; kk < 4; ++kk)
    a[kk] = *(const h8v*)(Ao5g + lrow * 128 + kk * 32 + lk * 8);
  const int n = 16 * w + lrow;
  f4v acc = {0.f, 0.f, 0.f, 0.f};
  #pragma unroll
  for (int kk = 0; kk < 4; ++kk) {
    h8v b = *(const h8v*)swz256c(OtL, n, kk * 32 + lk * 8);
    acc = mfma_(a[kk], b, acc);
  }
  #pragma unroll
  for (int j = 0; j < 4; ++j) {
    float v = acc[j];
    v = v * rcp_(1.0f + __expf(-v));
    rch_b[(lk * 4 + j) * 64 + n] = v;   // s = lk*4+j in [0,16)
  }
}

__global__ __launch_bounds__(512, 4)
void swarm_attn_mfma(const float* __restrict__ x, const float* __restrict__ L,
                     const f16* __restrict__ wts, float* __restrict__ rch)
{
  __shared__ f16 Xt[64 * 128];  // X^T / R^T [n][k] swz256
  __shared__ f16 Qt[64 * 128];  // Q^T [n][r]; reused as O^T after S
  __shared__ f16 Kt[64 * 128];  // K^T [m][r]
  __shared__ f16 Vb[128 * 64];  // V [r][m] swz128
  __shared__ f16 Ps[64 * 64];   // P [n][m] swz128
  __shared__ float s_inv;

  const int b = blockIdx.x;
  const int tid = threadIdx.x;
  const int w = tid >> 6, lane = tid & 63;

  // stage layer-1 X^T [n][f], zero-padded to K=32
  for (int e = tid; e < 64 * 32; e += 512) {
    const int n = e >> 5, f = e & 31;
    const float v = (f < 8) ? x[(size_t)b * 512 + f * 64 + n] : 0.f;
    *swz256(Xt, n, f) = (f16)v;
  }
  if (w == 0) {
    const float lv = L[(size_t)b * 512 + lane];
    const unsigned long long msk = __ballot(lv >= 1.0f);
    if (lane == 0) s_inv = __frsqrt_rn((float)(__popcll(msk) + 1));
  }
  __syncthreads();
  const float is = s_inv;

  // -------- Layer 1 (K = 32 padded) --------
  mm_WX<1, 0>(wts + OFF_WQ, Xt, Qt, w, lane);
  mm_WX<1, 0>(wts + OFF_WK, Xt, Kt, w, lane);
  mm_VT<1>  (wts + OFF_WV, Xt, Vb, w, lane);
  __syncthreads();
  if (w < 4) s_softmax(Qt, Kt, Ps, is, w, lane);
  __syncthreads();
  mm_PV(Vb, Ps, Qt, w, lane);                 // O^T -> Qt
  __syncthreads();
  mm_WX<4, 1>(wts + OFF_AO, Qt, Xt, w, lane); // R^T -> Xt
  __syncthreads();

  // -------- Layer 2 --------
  mm_WX<4, 0>(wts + OFF_AQ1, Xt, Qt, w, lane);
  mm_WX<4, 0>(wts + OFF_AK1, Xt, Kt, w, lane);
  mm_VT<4>  (wts + OFF_AV1, Xt, Vb, w, lane);
  __syncthreads();
  if (w < 4) s_softmax(Qt, Kt, Ps, is, w, lane);
  __syncthreads();
  mm_PV(Vb, Ps, Qt, w, lane);
  __syncthreads();
  mm_WX<4, 1>(wts + OFF_AO1, Qt, Xt, w, lane);
  __syncthreads();

  // -------- Layer 3 --------
  mm_WX<4, 0>(wts + OFF_AQ5, Xt, Qt, w, lane);
  mm_WX<4, 0>(wts + OFF_AK5, Xt, Kt, w, lane);
  mm_VT<4>  (wts + OFF_AV5, Xt, Vb, w, lane);
  __syncthreads();
  if (w < 4) s_softmax(Qt, Kt, Ps, is, w, lane);
  __syncthreads();
  mm_PV(Vb, Ps, Qt, w, lane);
  __syncthreads();
  if (w < 4) mm_final(wts + OFF_AO5, Qt, rch + (size_t)b * 1024, w, lane);
}

// Convert all weights to fp16 (layer-1 zero-padded 8->32)
__global__ void conv_wts(const float* Aq, const float* Ak, const float* Av,
                         const float* Aq1, const float* Ak1, const float* Av1,
                         const float* Aq5, const float* Ak5, const float* Av5,
                         const float* Ao, const float* Ao1, const float* Ao5,
                         f16* wts)
{
  const int t = blockIdx.x * 256 + threadIdx.x;
  if (t >= WTS_TOTAL) return;
  float v;
  if (t < 12288) {
    const int m = t >> 12, idx = t & 4095, r = idx >> 5, f = idx & 31;
    const float* W = (m == 0) ? Aq : (m == 1) ? Ak : Av;
    v = (f < 8) ? W[r * 8 + f] : 0.f;
  } else if (t < 143360) {
    const int idx = t - 12288, m = idx >> 14, e = idx & 16383;
    const float* W = (m == 0) ? Aq1 : (m == 1) ? Ak1 : (m == 2) ? Av1 :
                     (m == 3) ? Aq5 : (m == 4) ? Ak5 : (m == 5) ? Av5 :
                     (m == 6) ? Ao : Ao1;
    v = W[e];
  } else {
    v = Ao5[t - 143360];
  }
  wts[t] = (f16)v;
}

// Stage A: per swarm, channel-sum M_g (4x64x64) + row/col sums of squares
#define ASTR 65
__global__ __launch_bounds__(256, 1)
void reduce_kernel(const float* __restrict__ rch, float* __restrict__ Mw,
                   float* __restrict__ rsw, float* __restrict__ csw)
{
  __shared__ float Msh[4 * 64 * ASTR];
  const int s = blockIdx.x, t = threadIdx.x;
  for (int e = t; e < 16384; e += 256) {
    const int j = e & 63, i = (e >> 6) & 63, g = e >> 12;
    const float* p = rch + ((size_t)s * 64 + i) * 1024 + (4 * g) * 64 + j;
    const float v = p[0] + p[64] + p[128] + p[192];
    Msh[(g * 64 + i) * ASTR + j] = v;
    Mw[(size_t)s * 16384 + e] = v;        // [s][g][i][j]
  }
  __syncthreads();
  const int g = t >> 6, i = t & 63;
  float r2 = 0.f, c2 = 0.f;
  for (int j = 0; j < 64; ++j) {
    const float a = Msh[(g * 64 + i) * ASTR + j];
    const float bb = Msh[(g * 64 + j) * ASTR + i];
    r2 = fmaf(a, a, r2);
    c2 = fmaf(bb, bb, c2);
  }
  rsw[s * 256 + g * 64 + i] = r2;
  csw[s * 256 + g * 64 + i] = c2;
}

// Stage B: fully-parallel expansion to the 256x256 output per swarm (no rch reads)
__global__ __launch_bounds__(256, 1)
void expand_kernel(const float* __restrict__ Mw, const float* __restrict__ rsw,
                   const float* __restrict__ csw, float* __restrict__ out)
{
  const size_t e = ((size_t)blockIdx.x * 256 + threadIdx.x) * 4;
  const int s = (int)(e >> 16);
  const int rem = (int)(e & 65535);
  const int u = rem >> 8, v0 = rem & 255;
  const int ub = u >> 7, ii = (u & 127) >> 1, p = u & 1;
  const float* Ms = Mw + (size_t)s * 16384;
  float4 o;
  float* po = &o.x;
  #pragma unroll
  for (int c = 0; c < 4; ++c) {
    const int v = v0 + c;
    const int vb = v >> 7, jj = (v & 127) >> 1, q = v & 1;
    float val = 0.f;
    if (u == v) {
      val = rsw[s * 256 + (2 * ub) * 64 + ii] + rsw[s * 256 + (2 * ub + 1) * 64 + ii]
          + csw[s * 256 + ub * 64 + ii] + csw[s * 256 + (2 + ub) * 64 + ii];
    } else if (p == q) {
      const int g = 2 * ub + vb, gp = 2 * vb + ub;
      const float a = Ms[g * 4096 + ii * 64 + jj];
      const float bb = Ms[gp * 4096 + jj * 64 + ii];
      val = -(a * a + bb * bb);
    }
    po[c] = val;
  }
  *(float4*)(out + e) = o;
}

extern "C" void kernel_launch(void* const* d_in, const int* in_sizes, int n_in,
                              void* d_out, int out_size, void* d_ws, size_t ws_size,
                              hipStream_t stream)
{
  const float* x   = (const float*)d_in[0];
  const float* L   = (const float*)d_in[1];
  const float* Aq  = (const float*)d_in[2];
  const float* Ak  = (const float*)d_in[3];
  const float* Av  = (const float*)d_in[4];
  const float* Aq1 = (const float*)d_in[5];
  const float* Ak1 = (const float*)d_in[6];
  const float* Av1 = (const float*)d_in[7];
  const float* Aq5 = (const float*)d_in[8];
  const float* Ak5 = (const float*)d_in[9];
  const float* Av5 = (const float*)d_in[10];
  const float* Ao  = (const float*)d_in[11];
  const float* Ao1 = (const float*)d_in[12];
  const float* Ao5 = (const float*)d_in[13];

  // ws: fp16 weights (290816 B) | Mw 128*16384 f32 (8.39 MB) | rsw | csw
  f16* wts = (f16*)d_ws;
  float* Mw  = (float*)((char*)d_ws + (size_t)WTS_TOTAL * 2);
  float* rsw = Mw + (size_t)128 * 16384;
  float* csw = rsw + 128 * 256;
  // rch (8192x16x64 f32 = 33.55 MB) staged in d_out — exactly out_size; expand_kernel
  // reads only Mw/rsw/csw, so overwriting d_out afterwards is race-free.
  float* rch = (float*)d_out;

  conv_wts<<<(WTS_TOTAL + 255) / 256, 256, 0, stream>>>(Aq, Ak, Av, Aq1, Ak1, Av1,
                                                        Aq5, Ak5, Av5, Ao, Ao1, Ao5, wts);
  swarm_attn_mfma<<<8192, 512, 0, stream>>>(x, L, wts, rch);
  reduce_kernel<<<128, 256, 0, stream>>>(rch, Mw, rsw, csw);
  expand_kernel<<<8192, 256, 0, stream>>>(Mw, rsw, csw, (float*)d_out);
}

// Round 6
// 332.198 us; speedup vs baseline: 15.6819x; 1.2302x over previous
//
#include <hip/hip_runtime.h>
#include <hip/hip_bf16.h>

typedef _Float16 f16;
typedef __attribute__((ext_vector_type(8))) _Float16 h8v;   // 8 fp16 = 4 VGPR
typedef __attribute__((ext_vector_type(4))) float f4v;      // 4 f32
typedef __attribute__((ext_vector_type(16))) float f16acc;  // 32x32 accumulator

// fp16 weight workspace layout (elements).
// L1 (128x16, frag-major, 4 frags x 512) and 128x128 (frag-major, 32 frags x 512).
// Frag-major: frag fi = rt*(K/16)+kk holds lane l -> row rt*32+(l&31), k = kk*16+(l>>5)*8+j
// at offset fi*512 + l*8 + j  (one coalesced 1024B chunk per fragment).
#define OFF_WQ  0
#define OFF_WK  2048
#define OFF_WV  4096
#define OFF_AQ1 6144
#define OFF_AK1 22528
#define OFF_AV1 38912
#define OFF_AQ5 55296
#define OFF_AK5 71680
#define OFF_AV5 88064
#define OFF_AO  104448
#define OFF_AO1 120832
#define OFF_AO5 137216      // Ao5 stays row-major 16x128
#define WTS_TOTAL 139264

__device__ __forceinline__ f4v mfma16_(h8v a, h8v b, f4v c) {
  return __builtin_amdgcn_mfma_f32_16x16x32_f16(a, b, c, 0, 0, 0);
}
__device__ __forceinline__ f16acc mfma32_(h8v a, h8v b, f16acc c) {
  return __builtin_amdgcn_mfma_f32_32x32x16_f16(a, b, c, 0, 0, 0);
}
__device__ __forceinline__ float rcp_(float x) { return __builtin_amdgcn_rcpf(x); }
__device__ __forceinline__ unsigned int pk2(float a, float b) {
  __fp16 __attribute__((ext_vector_type(2))) h2 = __builtin_amdgcn_cvt_pkrtz(a, b);
  return *reinterpret_cast<unsigned int*>(&h2);
}
__device__ __forceinline__ f16acc zero16() {
  f16acc z;
  #pragma unroll
  for (int i = 0; i < 16; ++i) z[i] = 0.f;
  return z;
}

// XOR-swizzled LDS addressing: pitch 256B ([64][128] f16) and 128B ([*][64] f16)
__device__ __forceinline__ f16* swz256(f16* b, int n, int k) {
  int byte = (n << 8) + (k << 1); byte ^= (n & 7) << 4;
  return (f16*)((char*)b + byte);
}
__device__ __forceinline__ const f16* swz256c(const f16* b, int n, int k) {
  int byte = (n << 8) + (k << 1); byte ^= (n & 7) << 4;
  return (const f16*)((const char*)b + byte);
}
__device__ __forceinline__ f16* swz128(f16* b, int r, int m) {
  int byte = (r << 7) + (m << 1); byte ^= (r & 7) << 4;
  return (f16*)((char*)b + byte);
}
__device__ __forceinline__ const f16* swz128c(const f16* b, int r, int m) {
  int byte = (r << 7) + (m << 1); byte ^= (r & 7) << 4;
  return (const f16*)((const char*)b + byte);
}

// ACT: 0 sigmoid, 1 silu, 2 none — f32 (v_rcp), packed to 4 f16
template<int ACT>
__device__ __forceinline__ unsigned long long pack4act(f4v acc) {
  float v[4];
  #pragma unroll
  for (int j = 0; j < 4; ++j) {
    float t = acc[j];
    if (ACT == 0)      t = rcp_(1.0f + __expf(-t));
    else if (ACT == 1) t = t * rcp_(1.0f + __expf(-t));
    v[j] = t;
  }
  union { unsigned long long u64; unsigned int u32[2]; } u;
  u.u32[0] = pk2(v[0], v[1]);
  u.u32[1] = pk2(v[2], v[3]);
  return u.u64;
}

// Fused Q,K,V via 32x32x16. Wave w: Q/K tile rows 32(w>>1) x cols n 32(w&1);
// V^T tile rows m 32(w&1) x cols r 32(w>>1). X-frags (from Xt) shared by all three:
// same register is B-operand (col=lane&31) for Q/K and A-operand (row=lane&31) for V^T.
// Q^T,K^T -> swz256 [n][r]; V -> swz128 [r][m]. All with sigmoid.
template<int NKK>   // K = NKK*16
__device__ __forceinline__ void mm_qkv(const f16* __restrict__ Wq,
                                       const f16* __restrict__ Wk,
                                       const f16* __restrict__ Wv,
                                       const f16* __restrict__ Xt,
                                       f16* __restrict__ Qt, f16* __restrict__ Kt,
                                       f16* __restrict__ Vb, int w, int lane)
{
  const int l31 = lane & 31, lh = lane >> 5;
  const int rt = w >> 1, ct = w & 1;
  h8v xf[NKK];
  #pragma unroll
  for (int kk = 0; kk < NKK; ++kk)
    xf[kk] = *(const h8v*)swz256c(Xt, ct * 32 + l31, kk * 16 + lh * 8);
  f16acc aq = zero16(), ak = zero16(), av = zero16();
  #pragma unroll
  for (int kk = 0; kk < NKK; ++kk) {
    const int fo = (rt * NKK + kk) * 512 + lane * 8;
    h8v fq = *(const h8v*)(Wq + fo);
    h8v fk = *(const h8v*)(Wk + fo);
    h8v fv = *(const h8v*)(Wv + fo);
    aq = mfma32_(fq, xf[kk], aq);
    ak = mfma32_(fk, xf[kk], ak);
    av = mfma32_(xf[kk], fv, av);     // V^T = X^T · Av^T
  }
  const int n = ct * 32 + l31;
  #pragma unroll
  for (int q = 0; q < 4; ++q) {
    const int rr = rt * 32 + q * 8 + lh * 4;   // Q/K rows (r); V^T rows are m
    f4v t;
    t = (f4v){aq[4*q], aq[4*q+1], aq[4*q+2], aq[4*q+3]};
    *(unsigned long long*)swz256(Qt, n, rr) = pack4act<0>(t);
    t = (f4v){ak[4*q], ak[4*q+1], ak[4*q+2], ak[4*q+3]};
    *(unsigned long long*)swz256(Kt, n, rr) = pack4act<0>(t);
    t = (f4v){av[4*q], av[4*q+1], av[4*q+2], av[4*q+3]};
    *(unsigned long long*)swz128(Vb, rt * 32 + l31, ct * 32 + q * 8 + lh * 4) = pack4act<0>(t);
  }
}

// O = V @ P^T via 32x32x16. K = 64 (4 kk). Output O^T[n][r] swz256, no act.
__device__ __forceinline__ void mm_pv32(const f16* __restrict__ Vb,
                                        const f16* __restrict__ Ps,
                                        f16* __restrict__ Ot, int w, int lane)
{
  const int l31 = lane & 31, lh = lane >> 5;
  const int rt = w >> 1, ct = w & 1;
  f16acc acc = zero16();
  #pragma unroll
  for (int kk = 0; kk < 4; ++kk) {
    h8v a = *(const h8v*)swz128c(Vb, rt * 32 + l31, kk * 16 + lh * 8);
    h8v b = *(const h8v*)swz128c(Ps, ct * 32 + l31, kk * 16 + lh * 8);
    acc = mfma32_(a, b, acc);
  }
  const int n = ct * 32 + l31;
  #pragma unroll
  for (int q = 0; q < 4; ++q) {
    f4v t = (f4v){acc[4*q], acc[4*q+1], acc[4*q+2], acc[4*q+3]};
    *(unsigned long long*)swz256(Ot, n, rt * 32 + q * 8 + lh * 4) = pack4act<2>(t);
  }
}

// R = silu(Ao @ O) via 32x32x16, K = 128. Output R^T[n][s] swz256 -> Xt.
__device__ __forceinline__ void mm_ao32(const f16* __restrict__ Ao,
                                        const f16* __restrict__ Ot,
                                        f16* __restrict__ Rt, int w, int lane)
{
  const int l31 = lane & 31, lh = lane >> 5;
  const int st = w >> 1, ct = w & 1;
  f16acc acc = zero16();
  #pragma unroll
  for (int kk = 0; kk < 8; ++kk) {
    h8v a = *(const h8v*)(Ao + (st * 8 + kk) * 512 + lane * 8);
    h8v b = *(const h8v*)swz256c(Ot, ct * 32 + l31, kk * 16 + lh * 8);
    acc = mfma32_(a, b, acc);
  }
  const int n = ct * 32 + l31;
  #pragma unroll
  for (int q = 0; q < 4; ++q) {
    f4v t = (f4v){acc[4*q], acc[4*q+1], acc[4*q+2], acc[4*q+3]};
    *(unsigned long long*)swz256(Rt, n, st * 32 + q * 8 + lh * 4) = pack4act<1>(t);
  }
}

// S^T[m][n] = sum_r K[r][m] Q[r][n] (16x16 path), softmax over m, P -> Ps[n][m].
// Waves 0..3; wave w owns n-tile w. (Unchanged from validated round-5 kernel.)
__device__ __forceinline__ void s_softmax(const f16* __restrict__ QtL,
                                          const f16* __restrict__ KtL,
                                          f16* __restrict__ PsL,
                                          float is, int w, int lane)
{
  const int lrow = lane & 15, lk = lane >> 4;
  const int n = 16 * w + lrow;
  h8v bq[4];
  #pragma unroll
  for (int kk = 0; kk < 4; ++kk)
    bq[kk] = *(const h8v*)swz256c(QtL, n, kk * 32 + lk * 8);
  f4v acc[4];
  #pragma unroll
  for (int mt = 0; mt < 4; ++mt) {
    acc[mt] = (f4v){0.f, 0.f, 0.f, 0.f};
    #pragma unroll
    for (int kk = 0; kk < 4; ++kk) {
      h8v ak = *(const h8v*)swz256c(KtL, mt * 16 + lrow, kk * 32 + lk * 8);
      acc[mt] = mfma16_(ak, bq[kk], acc[mt]);
    }
  }
  float mx = -1e30f;
  #pragma unroll
  for (int mt = 0; mt < 4; ++mt)
    #pragma unroll
    for (int j = 0; j < 4; ++j) { acc[mt][j] *= is; mx = fmaxf(mx, acc[mt][j]); }
  mx = fmaxf(mx, __shfl_xor(mx, 16));
  mx = fmaxf(mx, __shfl_xor(mx, 32));
  float sm = 0.f;
  #pragma unroll
  for (int mt = 0; mt < 4; ++mt)
    #pragma unroll
    for (int j = 0; j < 4; ++j) { acc[mt][j] = __expf(acc[mt][j] - mx); sm += acc[mt][j]; }
  sm += __shfl_xor(sm, 16);
  sm += __shfl_xor(sm, 32);
  const float inv = rcp_(sm);
  #pragma unroll
  for (int mt = 0; mt < 4; ++mt) {
    union { unsigned long long u64; unsigned int u32[2]; } u;
    u.u32[0] = pk2(acc[mt][0] * inv, acc[mt][1] * inv);
    u.u32[1] = pk2(acc[mt][2] * inv, acc[mt][3] * inv);
    *(unsigned long long*)swz128(PsL, n, mt * 16 + lk * 4) = u.u64;
  }
}

// Final: rch[b][s][n] = silu(Ao5(16x128) @ O(128x64)), fp32. Waves 0..3 (16x16 path).
__device__ __forceinline__ void mm_final(const f16* __restrict__ Ao5g,
                                         const f16* __restrict__ OtL,
                                         float* __restrict__ rch_b, int w, int lane)
{
  const int lrow = lane & 15, lk = lane >> 4;
  h8v a[4];
  #pragma unroll
  for (int kk = 0; kk < 4; ++kk)
    a[kk] = *(const h8v*)(Ao5g + lrow * 128 + kk * 32 + lk * 8);
  const int n = 16 * w + lrow;
  f4v acc = {0.f, 0.f, 0.f, 0.f};
  #pragma unroll
  for (int kk = 0; kk < 4; ++kk) {
    h8v b = *(const h8v*)swz256c(OtL, n, kk * 32 + lk * 8);
    acc = mfma16_(a[kk], b, acc);
  }
  #pragma unroll
  for (int j = 0; j < 4; ++j) {
    float v = acc[j];
    v = v * rcp_(1.0f + __expf(-v));
    rch_b[(lk * 4 + j) * 64 + n] = v;
  }
}

__global__ __launch_bounds__(512, 4)
void swarm_attn_mfma(const float* __restrict__ x, const float* __restrict__ L,
                     const f16* __restrict__ wts, float* __restrict__ rch)
{
  __shared__ f16 Xt[64 * 128];  // X^T / R^T [n][k] swz256
  __shared__ f16 Qt[64 * 128];  // Q^T [n][r]; reused as O^T after softmax
  __shared__ f16 Kt[64 * 128];  // K^T [m][r]
  __shared__ f16 Vb[128 * 64];  // V [r][m] swz128
  __shared__ f16 Ps[64 * 64];   // P [n][m] swz128
  __shared__ float s_inv;

  const int b = blockIdx.x;
  const int tid = threadIdx.x;
  const int w = tid >> 6, lane = tid & 63;

  // stage layer-1 X^T [n][f], zero-padded to K=16 (u32 = 2 f16 per thread)
  {
    const int n = tid >> 3, c = tid & 7;
    unsigned int val = 0;
    if (c < 4) {
      const float a  = x[(size_t)b * 512 + (2 * c) * 64 + n];
      const float bb = x[(size_t)b * 512 + (2 * c + 1) * 64 + n];
      val = pk2(a, bb);
    }
    *(unsigned int*)swz256(Xt, n, 2 * c) = val;
  }
  if (w == 0) {
    const float lv = L[(size_t)b * 512 + lane];
    const unsigned long long msk = __ballot(lv >= 1.0f);
    if (lane == 0) s_inv = __frsqrt_rn((float)(__popcll(msk) + 1));
  }
  __syncthreads();
  const float is = s_inv;

  // -------- Layer 1 (K = 16 padded) --------
  mm_qkv<1>(wts + OFF_WQ, wts + OFF_WK, wts + OFF_WV, Xt, Qt, Kt, Vb, w, lane);
  __syncthreads();
  if (w < 4) s_softmax(Qt, Kt, Ps, is, w, lane);
  __syncthreads();
  mm_pv32(Vb, Ps, Qt, w, lane);               // O^T -> Qt
  __syncthreads();
  mm_ao32(wts + OFF_AO, Qt, Xt, w, lane);     // R^T -> Xt
  __syncthreads();

  // -------- Layer 2 (K = 128) --------
  mm_qkv<8>(wts + OFF_AQ1, wts + OFF_AK1, wts + OFF_AV1, Xt, Qt, Kt, Vb, w, lane);
  __syncthreads();
  if (w < 4) s_softmax(Qt, Kt, Ps, is, w, lane);
  __syncthreads();
  mm_pv32(Vb, Ps, Qt, w, lane);
  __syncthreads();
  mm_ao32(wts + OFF_AO1, Qt, Xt, w, lane);
  __syncthreads();

  // -------- Layer 3 (K = 128) --------
  mm_qkv<8>(wts + OFF_AQ5, wts + OFF_AK5, wts + OFF_AV5, Xt, Qt, Kt, Vb, w, lane);
  __syncthreads();
  if (w < 4) s_softmax(Qt, Kt, Ps, is, w, lane);
  __syncthreads();
  mm_pv32(Vb, Ps, Qt, w, lane);
  __syncthreads();
  if (w < 4) mm_final(wts + OFF_AO5, Qt, rch + (size_t)b * 1024, w, lane);
}

// Convert weights to fp16: frag-major for the eleven MFMA-32 matrices, row-major Ao5.
__global__ void conv_wts(const float* Aq, const float* Ak, const float* Av,
                         const float* Aq1, const float* Ak1, const float* Av1,
                         const float* Aq5, const float* Ak5, const float* Av5,
                         const float* Ao, const float* Ao1, const float* Ao5,
                         f16* wts)
{
  const int t = blockIdx.x * 256 + threadIdx.x;
  if (t >= WTS_TOTAL) return;
  float v;
  if (t < 6144) {                       // L1: 128x16 (padded from 8), 4 frags each
    const int m = t >> 11, idx = t & 2047;
    const int fi = idx >> 9, rem = idx & 511, lane = rem >> 3, j = rem & 7;
    const int r = fi * 32 + (lane & 31), k = (lane >> 5) * 8 + j;
    const float* W = (m == 0) ? Aq : (m == 1) ? Ak : Av;
    v = (k < 8) ? W[r * 8 + k] : 0.f;
  } else if (t < 137216) {              // 8 matrices 128x128, 32 frags each
    const int m = (t - 6144) >> 14, idx = (t - 6144) & 16383;
    const int fi = idx >> 9, rem = idx & 511, lane = rem >> 3, j = rem & 7;
    const int rt = fi >> 3, kk = fi & 7;
    const int r = rt * 32 + (lane & 31), k = kk * 16 + (lane >> 5) * 8 + j;
    const float* W = (m == 0) ? Aq1 : (m == 1) ? Ak1 : (m == 2) ? Av1 :
                     (m == 3) ? Aq5 : (m == 4) ? Ak5 : (m == 5) ? Av5 :
                     (m == 6) ? Ao : Ao1;
    v = W[r * 128 + k];
  } else {
    v = Ao5[t - 137216];
  }
  wts[t] = (f16)v;
}

// Stage A: per swarm, channel-sum M_g (4x64x64) + row/col sums of squares
#define ASTR 65
__global__ __launch_bounds__(256, 1)
void reduce_kernel(const float* __restrict__ rch, float* __restrict__ Mw,
                   float* __restrict__ rsw, float* __restrict__ csw)
{
  __shared__ float Msh[4 * 64 * ASTR];
  const int s = blockIdx.x, t = threadIdx.x;
  for (int e = t; e < 16384; e += 256) {
    const int j = e & 63, i = (e >> 6) & 63, g = e >> 12;
    const float* p = rch + ((size_t)s * 64 + i) * 1024 + (4 * g) * 64 + j;
    const float v = p[0] + p[64] + p[128] + p[192];
    Msh[(g * 64 + i) * ASTR + j] = v;
    Mw[(size_t)s * 16384 + e] = v;        // [s][g][i][j]
  }
  __syncthreads();
  const int g = t >> 6, i = t & 63;
  float r2 = 0.f, c2 = 0.f;
  for (int j = 0; j < 64; ++j) {
    const float a = Msh[(g * 64 + i) * ASTR + j];
    const float bb = Msh[(g * 64 + j) * ASTR + i];
    r2 = fmaf(a, a, r2);
    c2 = fmaf(bb, bb, c2);
  }
  rsw[s * 256 + g * 64 + i] = r2;
  csw[s * 256 + g * 64 + i] = c2;
}

// Stage B: fully-parallel expansion to the 256x256 output per swarm (no rch reads)
__global__ __launch_bounds__(256, 1)
void expand_kernel(const float* __restrict__ Mw, const float* __restrict__ rsw,
                   const float* __restrict__ csw, float* __restrict__ out)
{
  const size_t e = ((size_t)blockIdx.x * 256 + threadIdx.x) * 4;
  const int s = (int)(e >> 16);
  const int rem = (int)(e & 65535);
  const int u = rem >> 8, v0 = rem & 255;
  const int ub = u >> 7, ii = (u & 127) >> 1, p = u & 1;
  const float* Ms = Mw + (size_t)s * 16384;
  float4 o;
  float* po = &o.x;
  #pragma unroll
  for (int c = 0; c < 4; ++c) {
    const int v = v0 + c;
    const int vb = v >> 7, jj = (v & 127) >> 1, q = v & 1;
    float val = 0.f;
    if (u == v) {
      val = rsw[s * 256 + (2 * ub) * 64 + ii] + rsw[s * 256 + (2 * ub + 1) * 64 + ii]
          + csw[s * 256 + ub * 64 + ii] + csw[s * 256 + (2 + ub) * 64 + ii];
    } else if (p == q) {
      const int g = 2 * ub + vb, gp = 2 * vb + ub;
      const float a = Ms[g * 4096 + ii * 64 + jj];
      const float bb = Ms[gp * 4096 + jj * 64 + ii];
      val = -(a * a + bb * bb);
    }
    po[c] = val;
  }
  *(float4*)(out + e) = o;
}

extern "C" void kernel_launch(void* const* d_in, const int* in_sizes, int n_in,
                              void* d_out, int out_size, void* d_ws, size_t ws_size,
                              hipStream_t stream)
{
  const float* x   = (const float*)d_in[0];
  const float* L   = (const float*)d_in[1];
  const float* Aq  = (const float*)d_in[2];
  const float* Ak  = (const float*)d_in[3];
  const float* Av  = (const float*)d_in[4];
  const float* Aq1 = (const float*)d_in[5];
  const float* Ak1 = (const float*)d_in[6];
  const float* Av1 = (const float*)d_in[7];
  const float* Aq5 = (const float*)d_in[8];
  const float* Ak5 = (const float*)d_in[9];
  const float* Av5 = (const float*)d_in[10];
  const float* Ao  = (const float*)d_in[11];
  const float* Ao1 = (const float*)d_in[12];
  const float* Ao5 = (const float*)d_in[13];

  // ws: fp16 weights (278528 B) | Mw 128*16384 f32 | rsw | csw
  f16* wts = (f16*)d_ws;
  float* Mw  = (float*)((char*)d_ws + (size_t)WTS_TOTAL * 2);
  float* rsw = Mw + (size_t)128 * 16384;
  float* csw = rsw + 128 * 256;
  // rch (8192x16x64 f32 = 33.55 MB) staged in d_out; expand_kernel reads only
  // Mw/rsw/csw, so overwriting d_out afterwards is race-free.
  float* rch = (float*)d_out;

  conv_wts<<<(WTS_TOTAL + 255) / 256, 256, 0, stream>>>(Aq, Ak, Av, Aq1, Ak1, Av1,
                                                        Aq5, Ak5, Av5, Ao, Ao1, Ao5, wts);
  swarm_attn_mfma<<<8192, 512, 0, stream>>>(x, L, wts, rch);
  reduce_kernel<<<128, 256, 0, stream>>>(rch, Mw, rsw, csw);
  expand_kernel<<<8192, 256, 0, stream>>>(Mw, rsw, csw, (float*)d_out);
}